// Round 2
// baseline (459.540 us; speedup 1.0000x reference)
//
#include <hip/hip_runtime.h>
#include <hip/hip_cooperative_groups.h>

namespace cg = cooperative_groups;

#define NBLK 256
#define NTHR 1024

// ACT forward: one cooperative kernel, device-side halting loop.
// 256 blocks x 1024 thr = 4096 waves = one wave per row of H=4096.
// 1 block/CU (16 waves/CU) -> loosest possible cooperative co-residency.
__global__ __launch_bounds__(NTHR, 4) void act_kernel(
    const float* __restrict__ x, const float* __restrict__ s,
    const float* __restrict__ Wh, const float* __restrict__ bh,
    const float* __restrict__ Whalt, const float* __restrict__ bhalt,
    const float* __restrict__ Wo, const float* __restrict__ bo,
    float* __restrict__ out, float* __restrict__ ws)
{
    cg::grid_group grid = cg::this_grid();

    const int tid  = threadIdx.x;
    const int lane = tid & 63;
    const int wid  = tid >> 6;                  // wave in block, 0..15
    const int gw   = blockIdx.x * 16 + wid;     // row 0..4095
    const int gtid = blockIdx.x * NTHR + tid;

    float* buf0 = ws;           // state ping-pong buffers, 4096 floats each
    float* buf1 = ws + 4096;

    __shared__ float xl[4096];   // x reused every step -> LDS
    __shared__ float red[16];

    for (int k = tid; k < 4096; k += NTHR) xl[k] = x[k];

    // init: zero outputs, state(step0) = s  (harness poisons, we must init)
    if (gtid < 8193) out[gtid] = 0.0f;
    if (gtid < 4096) buf1[gtid] = s[gtid];
    grid.sync();                // xl (block) + buf1/out (grid) ready

    const float  bhalt0 = bhalt[0];
    const float* WhR    = Wh + (size_t)gw * 8193;
    const float* WoR    = Wo + (size_t)gw * 4096;
    const float  bh_r   = bh[gw];
    const float  bo_r   = bo[gw];

    float cum    = 0.0f;
    float ponder = 0.0f;

    for (int i = 0; i < 128; ++i) {
        const float* st = (i & 1) ? buf0 : buf1;   // prev state
        float*       ns = (i & 1) ? buf1 : buf0;   // new state

        // ---- phase A: new_state[gw] = Wh[gw] @ [flag, x, st] + bh[gw]
        float acc = 0.0f;
        #pragma unroll 8
        for (int k = lane; k < 4096; k += 64) acc += WhR[1 + k] * xl[k];
        #pragma unroll 8
        for (int k = lane; k < 4096; k += 64) acc += WhR[4097 + k] * st[k];
        #pragma unroll
        for (int off = 32; off > 0; off >>= 1) acc += __shfl_xor(acc, off, 64);
        if (lane == 0) {
            float v = acc + bh_r;
            if (i == 0) v += WhR[0];               // flag column, step 0 only
            ns[gw] = v;
        }
        grid.sync();   // the ONLY grid sync per iteration (others provably redundant)

        // ---- phase B: halt prob, computed redundantly & identically per block
        float part = 0.0f;
        #pragma unroll
        for (int k = tid; k < 4096; k += NTHR) part += Whalt[k] * ns[k];
        #pragma unroll
        for (int off = 32; off > 0; off >>= 1) part += __shfl_xor(part, off, 64);
        if (lane == 0) red[wid] = part;
        __syncthreads();
        float logit = bhalt0;
        #pragma unroll
        for (int j = 0; j < 16; ++j) logit += red[j];   // identical in all threads/blocks
        const float p         = 1.0f / (1.0f + expf(-logit));
        const bool  will_halt = (cum + p >= 0.99f) || (i == 127);
        const float w         = will_halt ? (1.0f - cum) : p;

        // ---- phase C: out += w*(Wo@ns + bo); hid += w*ns
        float acc2 = 0.0f;
        const float4* W4 = reinterpret_cast<const float4*>(WoR);
        const float4* n4 = reinterpret_cast<const float4*>(ns);
        #pragma unroll 8
        for (int k = lane; k < 1024; k += 64) {
            float4 wv = W4[k];
            float4 nv = n4[k];
            acc2 += wv.x * nv.x + wv.y * nv.y + wv.z * nv.z + wv.w * nv.w;
        }
        #pragma unroll
        for (int off = 32; off > 0; off >>= 1) acc2 += __shfl_xor(acc2, off, 64);
        if (lane == 0) {
            out[gw]        += w * (acc2 + bo_r);
            out[4096 + gw] += w * ns[gw];
        }

        if (will_halt) {                 // uniform across the whole grid
            ponder = (float)i + 1.0f + (1.0f - cum);
            break;
        }
        cum += p;
    }

    if (gtid == 0) out[8192] = ponder;
}

extern "C" void kernel_launch(void* const* d_in, const int* in_sizes, int n_in,
                              void* d_out, int out_size, void* d_ws, size_t ws_size,
                              hipStream_t stream) {
    const float* x     = (const float*)d_in[0];
    const float* s     = (const float*)d_in[1];
    const float* Wh    = (const float*)d_in[2];
    const float* bh    = (const float*)d_in[3];
    const float* Whalt = (const float*)d_in[4];
    const float* bhalt = (const float*)d_in[5];
    const float* Wo    = (const float*)d_in[6];
    const float* bo    = (const float*)d_in[7];
    float* out = (float*)d_out;
    float* ws  = (float*)d_ws;

    void* args[] = { (void*)&x, (void*)&s, (void*)&Wh, (void*)&bh,
                     (void*)&Whalt, (void*)&bhalt, (void*)&Wo, (void*)&bo,
                     (void*)&out, (void*)&ws };
    hipLaunchCooperativeKernel((void*)act_kernel, dim3(NBLK), dim3(NTHR),
                               args, 0, stream);
}